// Round 15
// baseline (160.907 us; speedup 1.0000x reference)
//
#include <hip/hip_runtime.h>
#include <hip/hip_bf16.h>

#define NPIX 16384   // 8*64*32 pixels: p = ((b*64 + t)*32 + h)
// D_IN=256, D_HID=640, DK=DV=DD=64, NH=8, taps=3x7=21, K_aug=21*64+64=1408

using short8 = __attribute__((ext_vector_type(8))) short;
using half8  = __attribute__((ext_vector_type(8))) _Float16;
using half4  = __attribute__((ext_vector_type(4))) _Float16;
using half2v = __attribute__((ext_vector_type(2))) _Float16;
using f32x4  = __attribute__((ext_vector_type(4))) float;

__device__ inline short bf16s(float x) {
  __hip_bfloat16 b = __float2bfloat16(x);
  return *reinterpret_cast<short*>(&b);
}

// ---- merged weight prep: W1/W2 -> bf16, Wt[d][k] f16, H2h f16 (one launch) ----
__global__ __launch_bounds__(256) void prep_all(const float* __restrict__ W1,
                                                const float* __restrict__ W2,
                                                const float* __restrict__ H1w,
                                                const float* __restrict__ P1,
                                                const float* __restrict__ H2w,
                                                __hip_bfloat16* __restrict__ W1_bf,
                                                __hip_bfloat16* __restrict__ W2_bf,
                                                _Float16* __restrict__ Wt,
                                                _Float16* __restrict__ H2h) {
  int i = blockIdx.x * 256 + threadIdx.x;
  const int n1 = 640 * 256, n2 = 640 * 640, n3 = 64 * 1408;
  if (i < n1) {
    W1_bf[i] = __float2bfloat16(W1[i]);
  } else if (i < n1 + n2) {
    W2_bf[i - n1] = __float2bfloat16(W2[i - n1]);
  } else if (i < n1 + n2 + n3) {
    int j = i - n1 - n2;
    int dd = j & 63, k = j >> 6;
    float v;
    if (k < 1344) { int t = k >> 6, c = k & 63; v = H1w[t * 4096 + c * 64 + dd]; }
    else          { int c = k - 1344;          v = P1[c * 64 + dd]; }
    Wt[(size_t)dd * 1408 + k] = (_Float16)v;
  } else if (i < n1 + n2 + n3 + 2048) {
    int j = i - n1 - n2 - n3;
    int t = j >> 6, dd = j & 63;
    H2h[j] = (t < 21) ? (_Float16)H2w[t * 64 + dd] : (_Float16)0.f;
  }
}

// ---- LDS-staged bf16 MFMA GEMM: C = silu(A[M,K] @ B[N,K]^T) -> bf16, A f32 ----
template<int K>
__global__ __launch_bounds__(256) void gemm_st(const float* __restrict__ Af,
                                               const short* __restrict__ B,
                                               __hip_bfloat16* __restrict__ Cb) {
  __shared__ short As[2][128][36];
  __shared__ short Bs[2][128][36];
  const int tid = threadIdx.x, lane = tid & 63, wid = tid >> 6;
  const int row0 = blockIdx.y * 128, col0 = blockIdx.x * 128;
  const int sr = tid >> 1, sc = (tid & 1) * 16;
  const int l15 = lane & 15, lk = (lane >> 4) * 8;
  const int wr = (wid >> 1) * 64, wc = (wid & 1) * 64;
  const int NS = K / 32;

  short8 aL, aH, bL, bH;
  auto loadTile = [&](int s) {
    const float* src = Af + (size_t)(row0 + sr) * K + s * 32 + sc;
    float4 f0 = *(const float4*)(src);
    float4 f1 = *(const float4*)(src + 4);
    float4 f2 = *(const float4*)(src + 8);
    float4 f3 = *(const float4*)(src + 12);
    aL[0] = bf16s(f0.x); aL[1] = bf16s(f0.y); aL[2] = bf16s(f0.z); aL[3] = bf16s(f0.w);
    aL[4] = bf16s(f1.x); aL[5] = bf16s(f1.y); aL[6] = bf16s(f1.z); aL[7] = bf16s(f1.w);
    aH[0] = bf16s(f2.x); aH[1] = bf16s(f2.y); aH[2] = bf16s(f2.z); aH[3] = bf16s(f2.w);
    aH[4] = bf16s(f3.x); aH[5] = bf16s(f3.y); aH[6] = bf16s(f3.z); aH[7] = bf16s(f3.w);
    const short* srcB = B + (size_t)(col0 + sr) * K + s * 32 + sc;
    bL = *(const short8*)srcB;
    bH = *(const short8*)(srcB + 8);
  };
  auto writeTile = [&](int buf) {
    *(short8*)&As[buf][sr][sc]     = aL;
    *(short8*)&As[buf][sr][sc + 8] = aH;
    *(short8*)&Bs[buf][sr][sc]     = bL;
    *(short8*)&Bs[buf][sr][sc + 8] = bH;
  };

  loadTile(0);
  writeTile(0);
  __syncthreads();

  f32x4 acc[4][4];
#pragma unroll
  for (int mi = 0; mi < 4; ++mi)
#pragma unroll
    for (int nj = 0; nj < 4; ++nj) acc[mi][nj] = (f32x4){0.f, 0.f, 0.f, 0.f};

  for (int s = 0; s < NS; ++s) {
    const int cur = s & 1;
    if (s + 1 < NS) loadTile(s + 1);
    short8 af[4], bfr[4];
#pragma unroll
    for (int mi = 0; mi < 4; ++mi)
      af[mi] = *(const short8*)&As[cur][wr + mi * 16 + l15][lk];
#pragma unroll
    for (int nj = 0; nj < 4; ++nj)
      bfr[nj] = *(const short8*)&Bs[cur][wc + nj * 16 + l15][lk];
#pragma unroll
    for (int mi = 0; mi < 4; ++mi)
#pragma unroll
      for (int nj = 0; nj < 4; ++nj)
        acc[mi][nj] = __builtin_amdgcn_mfma_f32_16x16x32_bf16(af[mi], bfr[nj], acc[mi][nj], 0, 0, 0);
    if (s + 1 < NS) writeTile(cur ^ 1);
    __syncthreads();
  }

  const int r0 = (lane >> 4) * 4;
#pragma unroll
  for (int mi = 0; mi < 4; ++mi)
#pragma unroll
    for (int nj = 0; nj < 4; ++nj)
#pragma unroll
      for (int r = 0; r < 4; ++r) {
        int row = row0 + wr + mi * 16 + r0 + r;
        int col = col0 + wc + nj * 16 + l15;
        float v = acc[mi][nj][r];
        v = v / (1.f + __expf(-v));
        Cb[(size_t)row * 640 + col] = __float2bfloat16(v);
      }
}

// ---- gemm2 + fused normalization: qn/kn/vn = l2norm slices as f16 ----
__global__ __launch_bounds__(256) void gemm_qkv(const short* __restrict__ Ab,
                                                const short* __restrict__ B,
                                                _Float16* __restrict__ qn,
                                                _Float16* __restrict__ kn,
                                                _Float16* __restrict__ vn) {
  __shared__ short As[2][128][36];
  __shared__ short Bs[2][128][36];
  const int tid = threadIdx.x, lane = tid & 63, wid = tid >> 6;
  const int row0 = blockIdx.y * 128, col0 = blockIdx.x * 128;
  const int sr = tid >> 1, sc = (tid & 1) * 16;
  const int l15 = lane & 15, lk = (lane >> 4) * 8;
  const int wr = (wid >> 1) * 64, wc = (wid & 1) * 64;
  const int NS = 20;   // 640/32

  short8 aL, aH, bL, bH;
  auto loadTile = [&](int s) {
    const short* src = Ab + (size_t)(row0 + sr) * 640 + s * 32 + sc;
    aL = *(const short8*)src;
    aH = *(const short8*)(src + 8);
    const short* srcB = B + (size_t)(col0 + sr) * 640 + s * 32 + sc;
    bL = *(const short8*)srcB;
    bH = *(const short8*)(srcB + 8);
  };
  auto writeTile = [&](int buf) {
    *(short8*)&As[buf][sr][sc]     = aL;
    *(short8*)&As[buf][sr][sc + 8] = aH;
    *(short8*)&Bs[buf][sr][sc]     = bL;
    *(short8*)&Bs[buf][sr][sc + 8] = bH;
  };

  loadTile(0);
  writeTile(0);
  __syncthreads();

  f32x4 acc[4][4];
#pragma unroll
  for (int mi = 0; mi < 4; ++mi)
#pragma unroll
    for (int nj = 0; nj < 4; ++nj) acc[mi][nj] = (f32x4){0.f, 0.f, 0.f, 0.f};

  for (int s = 0; s < NS; ++s) {
    const int cur = s & 1;
    if (s + 1 < NS) loadTile(s + 1);
    short8 af[4], bfr[4];
#pragma unroll
    for (int mi = 0; mi < 4; ++mi)
      af[mi] = *(const short8*)&As[cur][wr + mi * 16 + l15][lk];
#pragma unroll
    for (int nj = 0; nj < 4; ++nj)
      bfr[nj] = *(const short8*)&Bs[cur][wc + nj * 16 + l15][lk];
#pragma unroll
    for (int mi = 0; mi < 4; ++mi)
#pragma unroll
      for (int nj = 0; nj < 4; ++nj)
        acc[mi][nj] = __builtin_amdgcn_mfma_f32_16x16x32_bf16(af[mi], bfr[nj], acc[mi][nj], 0, 0, 0);
    if (s + 1 < NS) writeTile(cur ^ 1);
    __syncthreads();
  }

  const int r0g = (lane >> 4) * 4;
  const int ct = blockIdx.x;      // 0..3: heads 2ct,2ct+1; 4: k|v
  const int colh = wid & 1;
#pragma unroll
  for (int mi = 0; mi < 4; ++mi)
#pragma unroll
    for (int r = 0; r < 4; ++r) {
      float s = 0.f;
#pragma unroll
      for (int nj = 0; nj < 4; ++nj) s += acc[mi][nj][r] * acc[mi][nj][r];
      s += __shfl_xor(s, 1); s += __shfl_xor(s, 2);
      s += __shfl_xor(s, 4); s += __shfl_xor(s, 8);
      float inv = 1.f / sqrtf(s + 1e-6f);
      int row = row0 + wr + mi * 16 + r0g + r;
      _Float16* dst;
      if (ct < 4) dst = qn + (size_t)row * 512 + (ct * 2 + colh) * 64;
      else        dst = (colh == 0 ? kn : vn) + (size_t)row * 64;
#pragma unroll
      for (int nj = 0; nj < 4; ++nj)
        dst[nj * 16 + l15] = (_Float16)(acc[mi][nj][r] * inv);
    }
}

// ---------------- fused Phase A+B: kern MFMA -> Z (LDS) -> MFMA Gram -> out ----------------
__global__ __launch_bounds__(256, 4) void fused_kp(const _Float16* __restrict__ qn_g,
                                                   const _Float16* __restrict__ kn,
                                                   const _Float16* __restrict__ vn,
                                                   const _Float16* __restrict__ Wt,
                                                   const _Float16* __restrict__ H2h,
                                                   const float* __restrict__ Gw,
                                                   float* __restrict__ out) {
  __shared__ _Float16 qn_s[128][72];   // A: kern (kld); B: Zs+ZMs overlay
  __shared__ _Float16 win[66][72];     // A: kn window; B: vn window
  __shared__ _Float16 Bt[2][64][40];   // A: B-tile dbuf (80B rows); B: Gt+GwS

  float*    Zs  = (float*)&qn_s[0][0];                         // [16][21][8] f32 (10752B)
  _Float16* ZMs = (_Float16*)((char*)&qn_s[0][0] + 10752);     // [16][21][8] f16 (5376B)
  _Float16* Gt  = &Bt[0][0][0];                                // 2576 f16 (5152B)
  _Float16* GwS = &Bt[0][0][0] + 2576;                         // [21][64] f16 (2688B)

  int tid = threadIdx.x, lane = tid & 63, wid = tid >> 6;
  int pb = blockIdx.x * 16;
  int h0 = pb & 31, t0 = (pb >> 5) & 63, batch = pb >> 11;
  const int sd = tid >> 2, skq = (tid & 3) * 8;
  const int rt0 = wid * 2;
  const int l15 = lane & 15, lk = (lane >> 4) * 8;

  // --- q rows into registers with STATIC names (rule #20) ---
  half8 q00, q01, q10, q11;   // q[rt][half]
  int pix0, pix1;
  {
    int grow0 = (rt0 + 0) * 16 + l15;
    int grow1 = (rt0 + 1) * 16 + l15;
    pix0 = grow0 >> 3; pix1 = grow1 >> 3;
    const _Float16* b = qn_g + (size_t)pb * 512;
    q00 = *(const half8*)(b + grow0 * 64 + lk);
    q01 = *(const half8*)(b + grow0 * 64 + 32 + lk);
    q10 = *(const half8*)(b + grow1 * 64 + lk);
    q11 = *(const half8*)(b + grow1 * 64 + 32 + lk);
  }

  // --- kn window ---
  for (int idx = tid; idx < 528; idx += 256) {
    int j = idx >> 3, c0 = (idx & 7) * 8;
    int dy = j / 22, hx = j % 22;
    int t = t0 - 1 + dy, h = h0 - 3 + hx;
    half8 v = {0, 0, 0, 0, 0, 0, 0, 0};
    if ((unsigned)t < 64u && (unsigned)h < 32u)
      v = *(const half8*)(kn + ((size_t)((batch * 64 + t) * 32 + h)) * 64 + c0);
    *(half8*)&win[j][c0] = v;
  }
  *(half8*)&Bt[0][sd][skq] = *(const half8*)(Wt + (size_t)sd * 1408 + skq);
  __syncthreads();

  // --- K-loop: 22 iterations x 2 steps (hf static 0/1); one barrier/step ---
  f32x4 acc[2][4];
#pragma unroll
  for (int rt = 0; rt < 2; ++rt)
#pragma unroll
    for (int nj = 0; nj < 4; ++nj) acc[rt][nj] = (f32x4){0.f, 0.f, 0.f, 0.f};

  for (int ss = 0; ss < 22; ++ss) {
    const int sA = ss * 2, sB = sA + 1;
    const int dy = ss / 7, dxx = ss % 7;     // valid for ss<21; unused at ss=21

    // ---- step A (even, hf=0, read buf0, write buf1) ----
    {
      half8 stage = *(const half8*)(Wt + (size_t)sd * 1408 + (sA + 1) * 32 + skq);
      half8 bfr[4];
#pragma unroll
      for (int nj = 0; nj < 4; ++nj)
        bfr[nj] = *(const half8*)&Bt[0][nj * 16 + l15][lk];
      half8 a0, a1;
      if (ss < 21) {
        a0 = q00 * *(const half8*)&win[dy * 22 + pix0 + dxx][lk];
        a1 = q10 * *(const half8*)&win[dy * 22 + pix1 + dxx][lk];
      } else {
        a0 = q00; a1 = q10;
      }
#pragma unroll
      for (int nj = 0; nj < 4; ++nj) {
        acc[0][nj] = __builtin_amdgcn_mfma_f32_16x16x32_f16(a0, bfr[nj], acc[0][nj], 0, 0, 0);
        acc[1][nj] = __builtin_amdgcn_mfma_f32_16x16x32_f16(a1, bfr[nj], acc[1][nj], 0, 0, 0);
      }
      *(half8*)&Bt[1][sd][skq] = stage;
      __syncthreads();
    }
    // ---- step B (odd, hf=1, read buf1, write buf0) ----
    {
      half8 stage;
      if (sB < 43)
        stage = *(const half8*)(Wt + (size_t)sd * 1408 + (sB + 1) * 32 + skq);
      half8 bfr[4];
#pragma unroll
      for (int nj = 0; nj < 4; ++nj)
        bfr[nj] = *(const half8*)&Bt[1][nj * 16 + l15][lk];
      half8 a0, a1;
      if (ss < 21) {
        a0 = q01 * *(const half8*)&win[dy * 22 + pix0 + dxx][32 + lk];
        a1 = q11 * *(const half8*)&win[dy * 22 + pix1 + dxx][32 + lk];
      } else {
        a0 = q01; a1 = q11;
      }
#pragma unroll
      for (int nj = 0; nj < 4; ++nj) {
        acc[0][nj] = __builtin_amdgcn_mfma_f32_16x16x32_f16(a0, bfr[nj], acc[0][nj], 0, 0, 0);
        acc[1][nj] = __builtin_amdgcn_mfma_f32_16x16x32_f16(a1, bfr[nj], acc[1][nj], 0, 0, 0);
      }
      if (sB < 43) *(half8*)&Bt[0][sd][skq] = stage;
      __syncthreads();
    }
  }

  // --- kern -> LDS (own rows), Z = kern @ H2^T via MFMA (own rows) ---
  _Float16* kld = &qn_s[0][0];
  const int r0 = (lane >> 4) * 4;
#pragma unroll
  for (int rt = 0; rt < 2; ++rt) {
    int growb = (rt0 + rt) * 16;
#pragma unroll
    for (int nj = 0; nj < 4; ++nj)
#pragma unroll
      for (int r = 0; r < 4; ++r)
        kld[(growb + r0 + r) * 72 + nj * 16 + l15] = (_Float16)acc[rt][nj][r];
  }

  f32x4 accZ[2][2];
#pragma unroll
  for (int rt = 0; rt < 2; ++rt)
#pragma unroll
    for (int ct = 0; ct < 2; ++ct) accZ[rt][ct] = (f32x4){0.f, 0.f, 0.f, 0.f};
#pragma unroll
  for (int k2 = 0; k2 < 2; ++k2) {
    half8 bz[2];
#pragma unroll
    for (int ct = 0; ct < 2; ++ct)
      bz[ct] = *(const half8*)(H2h + (ct * 16 + l15) * 64 + k2 * 32 + lk);
#pragma unroll
    for (int rt = 0; rt < 2; ++rt) {
      half8 az = *(const half8*)&kld[((rt0 + rt) * 16 + l15) * 72 + k2 * 32 + lk];
#pragma unroll
      for (int ct = 0; ct < 2; ++ct)
        accZ[rt][ct] = __builtin_amdgcn_mfma_f32_16x16x32_f16(az, bz[ct], accZ[rt][ct], 0, 0, 0);
    }
  }
  __syncthreads();   // B1: phase-A LDS reads done -> overlay safe

  // --- phase B staging: Zs (from accZ), vn window, GwS ---
#pragma unroll
  for (int rt = 0; rt < 2; ++rt)
#pragma unroll
    for (int ct = 0; ct < 2; ++ct) {
      int t = ct * 16 + l15;
      if (t < 21) {
#pragma unroll
        for (int r = 0; r < 4; ++r) {
          int grow = (rt0 + rt) * 16 + r0 + r;
          Zs[((grow >> 3) * 21 + t) * 8 + (grow & 7)] = accZ[rt][ct][r];
        }
      }
    }
  for (int idx = tid; idx < 528; idx += 256) {
    int j = idx >> 3, c0 = (idx & 7) * 8;
    int dy = j / 22, hx = j % 22;
    int t = t0 - 1 + dy, h = h0 - 3 + hx;
    half8 v = {0, 0, 0, 0, 0, 0, 0, 0};
    if ((unsigned)t < 64u && (unsigned)h < 32u)
      v = *(const half8*)(vn + ((size_t)((batch * 64 + t) * 32 + h)) * 64 + c0);
    *(half8*)&win[j][c0] = v;
  }
  for (int idx = tid; idx < 168; idx += 256) {
    int t = idx >> 3, c0 = (idx & 7) * 8;
    const float* g = Gw + t * 64 + c0;
    half8 o;
#pragma unroll
    for (int j = 0; j < 8; ++j) o[j] = (_Float16)g[j];
    *(half8*)&GwS[t * 64 + c0] = o;
  }
  __syncthreads();   // B2

  // --- Gt table via MFMA Gram: 15 upper-tri 16x16 tiles over 66 win rows ---
  {
    const half8 hz = {0, 0, 0, 0, 0, 0, 0, 0};
    int c = 0;
#pragma unroll
    for (int ti = 0; ti < 5; ++ti)
#pragma unroll
      for (int tj = ti; tj < 5; ++tj, ++c) {
        if ((c & 3) == wid) {     // wave-uniform branch
          f32x4 g = {0.f, 0.f, 0.f, 0.f};
          const int ra = ti * 16 + l15, rb = tj * 16 + l15;
#pragma unroll
          for (int k2 = 0; k2 < 2; ++k2) {
            half8 av = (ra < 66) ? *(const half8*)&win[ra][k2 * 32 + lk] : hz;
            half8 bv = (rb < 66) ? *(const half8*)&win[rb][k2 * 32 + lk] : hz;
            g = __builtin_amdgcn_mfma_f32_16x16x32_f16(av, bv, g, 0, 0, 0);
          }
#pragma unroll
          for (int r = 0; r < 4; ++r) {
            int j1 = ti * 16 + r0 + r, j2 = tj * 16 + l15;
            if (j1 < 66 && j2 < 66) {
              int dy1 = j1 / 22, x1 = j1 % 22;
              int dy2 = j2 / 22, x2 = j2 % 22;
              int d = x2 - x1 + 6;
              _Float16 val = (_Float16)g[r];
              if ((unsigned)d < 13u)
                Gt[(dy1 * 3 + dy2) * 286 + x1 * 13 + d] = val;
              if (ti != tj) {          // compile-time; mirror ordered pair (j2,j1)
                int d2 = 12 - d;
                if ((unsigned)d2 < 13u)
                  Gt[(dy2 * 3 + dy1) * 286 + x2 * 13 + d2] = val;
              }
            }
          }
        }
      }
  }
  __syncthreads();   // B3

  // --- ZM: thread = (pix = tid>>4, j = tid&15): t1 in {j, j+16 (j<5)} -> Zs reads shared ---
  {
    int pix = tid >> 4, j = tid & 15;
    int dy1a = j / 7, dx1a = j % 7, x1a = pix + dx1a;
    int t1b = j + 16;                      // valid when j < 5 (t1b in 16..20, dy=2)
    int dx1b = t1b % 7, x1b = pix + dx1b;  // dy1b == 2
    f32x4 s0a = {0.f,0.f,0.f,0.f}, s1a = {0.f,0.f,0.f,0.f};
    f32x4 s0b = {0.f,0.f,0.f,0.f}, s1b = {0.f,0.f,0.f,0.f};
#pragma unroll
    for (int t2 = 0; t2 < 21; ++t2) {
      f32x4 z0 = *(const f32x4*)&Zs[(pix * 21 + t2) * 8];
      f32x4 z1 = *(const f32x4*)&Zs[(pix * 21 + t2) * 8 + 4];
      float ma = (float)Gt[(dy1a * 3 + t2 / 7) * 286 + x1a * 13 + (t2 % 7) - dx1a + 6];
      s0a += ma * z0; s1a += ma * z1;
      if (j < 5) {
        float mb = (float)Gt[(2 * 3 + t2 / 7) * 286 + x1b * 13 + (t2 % 7) - dx1b + 6];
        s0b += mb * z0; s1b += mb * z1;
      }
    }
    half4 loA = {(_Float16)s0a[0], (_Float16)s0a[1], (_Float16)s0a[2], (_Float16)s0a[3]};
    half4 hiA = {(_Float16)s1a[0], (_Float16)s1a[1], (_Float16)s1a[2], (_Float16)s1a[3]};
    *(half4*)&ZMs[(pix * 21 + j) * 8]     = loA;
    *(half4*)&ZMs[(pix * 21 + j) * 8 + 4] = hiA;
    if (j < 5) {
      half4 loB = {(_Float16)s0b[0], (_Float16)s0b[1], (_Float16)s0b[2], (_Float16)s0b[3]};
      half4 hiB = {(_Float16)s1b[0], (_Float16)s1b[1], (_Float16)s1b[2], (_Float16)s1b[3]};
      *(half4*)&ZMs[(pix * 21 + t1b) * 8]     = loB;
      *(half4*)&ZMs[(pix * 21 + t1b) * 8 + 4] = hiB;
    }
  }
  __syncthreads();   // B4

  // --- out: thread = (pix = tid>>4, v-quad v0 = (tid&15)*4); z/zm amortized over 4 v ---
  {
    int pix = tid >> 4, v0 = (tid & 15) * 4;
    f32x4 A00 = {0.f,0.f,0.f,0.f}, A01 = {0.f,0.f,0.f,0.f};
    f32x4 A02 = {0.f,0.f,0.f,0.f}, A03 = {0.f,0.f,0.f,0.f};
    f32x4 A10 = {0.f,0.f,0.f,0.f}, A11 = {0.f,0.f,0.f,0.f};
    f32x4 A12 = {0.f,0.f,0.f,0.f}, A13 = {0.f,0.f,0.f,0.f};
#pragma unroll
    for (int t = 0; t < 21; ++t) {
      half4 sv = *(const half4*)&win[(t / 7) * 22 + pix + (t % 7)][v0];
      half4 gw = *(const half4*)&GwS[t * 64 + v0];
      f32x4 z0 = *(const f32x4*)&Zs[(pix * 21 + t) * 8];
      f32x4 z1 = *(const f32x4*)&Zs[(pix * 21 + t) * 8 + 4];
      half8 zm = *(const half8*)&ZMs[(pix * 21 + t) * 8];
      f32x4 m0 = {(float)zm[0], (float)zm[1], (float)zm[2], (float)zm[3]};
      f32x4 m1 = {(float)zm[4], (float)zm[5], (float)zm[6], (float)zm[7]};
      {
        float s = (float)sv[0], g = (float)gw[0];
        A00 += s * z0 + g * m0; A10 += s * z1 + g * m1;
      }
      {
        float s = (float)sv[1], g = (float)gw[1];
        A01 += s * z0 + g * m0; A11 += s * z1 + g * m1;
      }
      {
        float s = (float)sv[2], g = (float)gw[2];
        A02 += s * z0 + g * m0; A12 += s * z1 + g * m1;
      }
      {
        float s = (float)sv[3], g = (float)gw[3];
        A03 += s * z0 + g * m0; A13 += s * z1 + g * m1;
      }
    }
    float* dst = out + (size_t)(pb + pix) * 512 + v0 * 8;
    *(f32x4*)(dst + 0)  = A00; *(f32x4*)(dst + 4)  = A10;
    *(f32x4*)(dst + 8)  = A01; *(f32x4*)(dst + 12) = A11;
    *(f32x4*)(dst + 16) = A02; *(f32x4*)(dst + 20) = A12;
    *(f32x4*)(dst + 24) = A03; *(f32x4*)(dst + 28) = A13;
  }
}

extern "C" void kernel_launch(void* const* d_in, const int* in_sizes, int n_in,
                              void* d_out, int out_size, void* d_ws, size_t ws_size,
                              hipStream_t stream) {
  const float* x   = (const float*)d_in[0];
  const float* W1  = (const float*)d_in[1];
  const float* W2  = (const float*)d_in[2];
  const float* P1  = (const float*)d_in[3];
  const float* H1w = (const float*)d_in[4];
  const float* H2w = (const float*)d_in[5];
  const float* Gw  = (const float*)d_in[6];
  // d_in[7] = I — identity, folded algebraically.
  float* out = (float*)d_out;

  char* ws = (char*)d_ws;
  __hip_bfloat16* h_bf = (__hip_bfloat16*)(ws);             // 20,971,520
  _Float16* qn         = (_Float16*)(ws + 20971520);        // 16,777,216 (end 37,748,736)
  _Float16* kn         = (_Float16*)(ws + 37748736);        //  2,097,152
  _Float16* vn         = (_Float16*)(ws + 39845888);        //  2,097,152 (end 41,943,040)
  __hip_bfloat16* W1_bf= (__hip_bfloat16*)(ws + 41943040);  //    327,680
  __hip_bfloat16* W2_bf= (__hip_bfloat16*)(ws + 42270720);  //    819,200
  _Float16* Wt         = (_Float16*)(ws + 43089920);        //    180,224
  _Float16* H2h        = (_Float16*)(ws + 43270144);        //      4,096 (end 43,274,240)

  prep_all<<<dim3(2600), dim3(256), 0, stream>>>(W1, W2, H1w, P1, H2w,
                                                 W1_bf, W2_bf, Wt, H2h);

  gemm_st<256><<<dim3(5, 128), dim3(256), 0, stream>>>(x, (const short*)W1_bf, h_bf);
  gemm_qkv<<<dim3(5, 128), dim3(256), 0, stream>>>(
      (const short*)h_bf, (const short*)W2_bf, qn, kn, vn);

  fused_kp<<<dim3(NPIX / 16), dim3(256), 0, stream>>>(qn, kn, vn, Wt, H2h, Gw, out);
}

// Round 16
// 116.996 us; speedup vs baseline: 1.3753x; 1.3753x over previous
//
#include <hip/hip_runtime.h>
#include <hip/hip_bf16.h>

#define NPIX 16384   // 8*64*32 pixels: p = ((b*64 + t)*32 + h)
// D_IN=256, D_HID=640, DK=DV=DD=64, NH=8, taps=3x7=21, K_aug=21*64+64=1408

using short8 = __attribute__((ext_vector_type(8))) short;
using half8  = __attribute__((ext_vector_type(8))) _Float16;
using half4  = __attribute__((ext_vector_type(4))) _Float16;
using half2v = __attribute__((ext_vector_type(2))) _Float16;
using f32x4  = __attribute__((ext_vector_type(4))) float;

__device__ inline short bf16s(float x) {
  __hip_bfloat16 b = __float2bfloat16(x);
  return *reinterpret_cast<short*>(&b);
}

// ---- merged weight prep: W1/W2 -> bf16, Wt[d][k] f16, H2h f16 (one launch) ----
__global__ __launch_bounds__(256) void prep_all(const float* __restrict__ W1,
                                                const float* __restrict__ W2,
                                                const float* __restrict__ H1w,
                                                const float* __restrict__ P1,
                                                const float* __restrict__ H2w,
                                                __hip_bfloat16* __restrict__ W1_bf,
                                                __hip_bfloat16* __restrict__ W2_bf,
                                                _Float16* __restrict__ Wt,
                                                _Float16* __restrict__ H2h) {
  int i = blockIdx.x * 256 + threadIdx.x;
  const int n1 = 640 * 256, n2 = 640 * 640, n3 = 64 * 1408;
  if (i < n1) {
    W1_bf[i] = __float2bfloat16(W1[i]);
  } else if (i < n1 + n2) {
    W2_bf[i - n1] = __float2bfloat16(W2[i - n1]);
  } else if (i < n1 + n2 + n3) {
    int j = i - n1 - n2;
    int dd = j & 63, k = j >> 6;
    float v;
    if (k < 1344) { int t = k >> 6, c = k & 63; v = H1w[t * 4096 + c * 64 + dd]; }
    else          { int c = k - 1344;          v = P1[c * 64 + dd]; }
    Wt[(size_t)dd * 1408 + k] = (_Float16)v;
  } else if (i < n1 + n2 + n3 + 2048) {
    int j = i - n1 - n2 - n3;
    int t = j >> 6, dd = j & 63;
    H2h[j] = (t < 21) ? (_Float16)H2w[t * 64 + dd] : (_Float16)0.f;
  }
}

// ---- LDS-staged bf16 MFMA GEMM: C = silu(A[M,K] @ B[N,K]^T) -> bf16, A f32 ----
template<int K>
__global__ __launch_bounds__(256) void gemm_st(const float* __restrict__ Af,
                                               const short* __restrict__ B,
                                               __hip_bfloat16* __restrict__ Cb) {
  __shared__ short As[2][128][36];
  __shared__ short Bs[2][128][36];
  const int tid = threadIdx.x, lane = tid & 63, wid = tid >> 6;
  const int row0 = blockIdx.y * 128, col0 = blockIdx.x * 128;
  const int sr = tid >> 1, sc = (tid & 1) * 16;
  const int l15 = lane & 15, lk = (lane >> 4) * 8;
  const int wr = (wid >> 1) * 64, wc = (wid & 1) * 64;
  const int NS = K / 32;

  short8 aL, aH, bL, bH;
  auto loadTile = [&](int s) {
    const float* src = Af + (size_t)(row0 + sr) * K + s * 32 + sc;
    float4 f0 = *(const float4*)(src);
    float4 f1 = *(const float4*)(src + 4);
    float4 f2 = *(const float4*)(src + 8);
    float4 f3 = *(const float4*)(src + 12);
    aL[0] = bf16s(f0.x); aL[1] = bf16s(f0.y); aL[2] = bf16s(f0.z); aL[3] = bf16s(f0.w);
    aL[4] = bf16s(f1.x); aL[5] = bf16s(f1.y); aL[6] = bf16s(f1.z); aL[7] = bf16s(f1.w);
    aH[0] = bf16s(f2.x); aH[1] = bf16s(f2.y); aH[2] = bf16s(f2.z); aH[3] = bf16s(f2.w);
    aH[4] = bf16s(f3.x); aH[5] = bf16s(f3.y); aH[6] = bf16s(f3.z); aH[7] = bf16s(f3.w);
    const short* srcB = B + (size_t)(col0 + sr) * K + s * 32 + sc;
    bL = *(const short8*)srcB;
    bH = *(const short8*)(srcB + 8);
  };
  auto writeTile = [&](int buf) {
    *(short8*)&As[buf][sr][sc]     = aL;
    *(short8*)&As[buf][sr][sc + 8] = aH;
    *(short8*)&Bs[buf][sr][sc]     = bL;
    *(short8*)&Bs[buf][sr][sc + 8] = bH;
  };

  loadTile(0);
  writeTile(0);
  __syncthreads();

  f32x4 acc[4][4];
#pragma unroll
  for (int mi = 0; mi < 4; ++mi)
#pragma unroll
    for (int nj = 0; nj < 4; ++nj) acc[mi][nj] = (f32x4){0.f, 0.f, 0.f, 0.f};

  for (int s = 0; s < NS; ++s) {
    const int cur = s & 1;
    if (s + 1 < NS) loadTile(s + 1);
    short8 af[4], bfr[4];
#pragma unroll
    for (int mi = 0; mi < 4; ++mi)
      af[mi] = *(const short8*)&As[cur][wr + mi * 16 + l15][lk];
#pragma unroll
    for (int nj = 0; nj < 4; ++nj)
      bfr[nj] = *(const short8*)&Bs[cur][wc + nj * 16 + l15][lk];
#pragma unroll
    for (int mi = 0; mi < 4; ++mi)
#pragma unroll
      for (int nj = 0; nj < 4; ++nj)
        acc[mi][nj] = __builtin_amdgcn_mfma_f32_16x16x32_bf16(af[mi], bfr[nj], acc[mi][nj], 0, 0, 0);
    if (s + 1 < NS) writeTile(cur ^ 1);
    __syncthreads();
  }

  const int r0 = (lane >> 4) * 4;
#pragma unroll
  for (int mi = 0; mi < 4; ++mi)
#pragma unroll
    for (int nj = 0; nj < 4; ++nj)
#pragma unroll
      for (int r = 0; r < 4; ++r) {
        int row = row0 + wr + mi * 16 + r0 + r;
        int col = col0 + wc + nj * 16 + l15;
        float v = acc[mi][nj][r];
        v = v / (1.f + __expf(-v));
        Cb[(size_t)row * 640 + col] = __float2bfloat16(v);
      }
}

// ---- gemm2 + fused normalization: qn/kn/vn = l2norm slices as f16 ----
__global__ __launch_bounds__(256) void gemm_qkv(const short* __restrict__ Ab,
                                                const short* __restrict__ B,
                                                _Float16* __restrict__ qn,
                                                _Float16* __restrict__ kn,
                                                _Float16* __restrict__ vn) {
  __shared__ short As[2][128][36];
  __shared__ short Bs[2][128][36];
  const int tid = threadIdx.x, lane = tid & 63, wid = tid >> 6;
  const int row0 = blockIdx.y * 128, col0 = blockIdx.x * 128;
  const int sr = tid >> 1, sc = (tid & 1) * 16;
  const int l15 = lane & 15, lk = (lane >> 4) * 8;
  const int wr = (wid >> 1) * 64, wc = (wid & 1) * 64;
  const int NS = 20;   // 640/32

  short8 aL, aH, bL, bH;
  auto loadTile = [&](int s) {
    const short* src = Ab + (size_t)(row0 + sr) * 640 + s * 32 + sc;
    aL = *(const short8*)src;
    aH = *(const short8*)(src + 8);
    const short* srcB = B + (size_t)(col0 + sr) * 640 + s * 32 + sc;
    bL = *(const short8*)srcB;
    bH = *(const short8*)(srcB + 8);
  };
  auto writeTile = [&](int buf) {
    *(short8*)&As[buf][sr][sc]     = aL;
    *(short8*)&As[buf][sr][sc + 8] = aH;
    *(short8*)&Bs[buf][sr][sc]     = bL;
    *(short8*)&Bs[buf][sr][sc + 8] = bH;
  };

  loadTile(0);
  writeTile(0);
  __syncthreads();

  f32x4 acc[4][4];
#pragma unroll
  for (int mi = 0; mi < 4; ++mi)
#pragma unroll
    for (int nj = 0; nj < 4; ++nj) acc[mi][nj] = (f32x4){0.f, 0.f, 0.f, 0.f};

  for (int s = 0; s < NS; ++s) {
    const int cur = s & 1;
    if (s + 1 < NS) loadTile(s + 1);
    short8 af[4], bfr[4];
#pragma unroll
    for (int mi = 0; mi < 4; ++mi)
      af[mi] = *(const short8*)&As[cur][wr + mi * 16 + l15][lk];
#pragma unroll
    for (int nj = 0; nj < 4; ++nj)
      bfr[nj] = *(const short8*)&Bs[cur][wc + nj * 16 + l15][lk];
#pragma unroll
    for (int mi = 0; mi < 4; ++mi)
#pragma unroll
      for (int nj = 0; nj < 4; ++nj)
        acc[mi][nj] = __builtin_amdgcn_mfma_f32_16x16x32_bf16(af[mi], bfr[nj], acc[mi][nj], 0, 0, 0);
    if (s + 1 < NS) writeTile(cur ^ 1);
    __syncthreads();
  }

  const int r0g = (lane >> 4) * 4;
  const int ct = blockIdx.x;      // 0..3: heads 2ct,2ct+1; 4: k|v
  const int colh = wid & 1;
#pragma unroll
  for (int mi = 0; mi < 4; ++mi)
#pragma unroll
    for (int r = 0; r < 4; ++r) {
      float s = 0.f;
#pragma unroll
      for (int nj = 0; nj < 4; ++nj) s += acc[mi][nj][r] * acc[mi][nj][r];
      s += __shfl_xor(s, 1); s += __shfl_xor(s, 2);
      s += __shfl_xor(s, 4); s += __shfl_xor(s, 8);
      float inv = 1.f / sqrtf(s + 1e-6f);
      int row = row0 + wr + mi * 16 + r0g + r;
      _Float16* dst;
      if (ct < 4) dst = qn + (size_t)row * 512 + (ct * 2 + colh) * 64;
      else        dst = (colh == 0 ? kn : vn) + (size_t)row * 64;
#pragma unroll
      for (int nj = 0; nj < 4; ++nj)
        dst[nj * 16 + l15] = (_Float16)(acc[mi][nj][r] * inv);
    }
}

// ---------------- fused Phase A+B: kern MFMA -> Z (LDS) -> MFMA Gram -> out ----------------
__global__ __launch_bounds__(256, 4) void fused_kp(const _Float16* __restrict__ qn_g,
                                                   const _Float16* __restrict__ kn,
                                                   const _Float16* __restrict__ vn,
                                                   const _Float16* __restrict__ Wt,
                                                   const _Float16* __restrict__ H2h,
                                                   const float* __restrict__ Gw,
                                                   float* __restrict__ out) {
  __shared__ _Float16 qn_s[128][72];   // A: kern (kld); B: Zs+ZMs overlay
  __shared__ _Float16 win[66][72];     // A: kn window; B: vn window
  __shared__ _Float16 Bt[2][64][40];   // A: B-tile dbuf (80B rows); B: Gt+GwS

  float*    Zs  = (float*)&qn_s[0][0];                         // [16][21][8] f32 (10752B)
  _Float16* ZMs = (_Float16*)((char*)&qn_s[0][0] + 10752);     // [16][21][8] f16 (5376B)
  _Float16* Gt  = &Bt[0][0][0];                                // 2576 f16 (5152B)
  _Float16* GwS = &Bt[0][0][0] + 2576;                         // [21][64] f16 (2688B)

  int tid = threadIdx.x, lane = tid & 63, wid = tid >> 6;
  int pb = blockIdx.x * 16;
  int h0 = pb & 31, t0 = (pb >> 5) & 63, batch = pb >> 11;
  const int sd = tid >> 2, skq = (tid & 3) * 8;
  const int rt0 = wid * 2;
  const int l15 = lane & 15, lk = (lane >> 4) * 8;

  // --- q rows into registers with STATIC names (rule #20) ---
  half8 q00, q01, q10, q11;   // q[rt][half]
  int pix0, pix1;
  {
    int grow0 = (rt0 + 0) * 16 + l15;
    int grow1 = (rt0 + 1) * 16 + l15;
    pix0 = grow0 >> 3; pix1 = grow1 >> 3;
    const _Float16* b = qn_g + (size_t)pb * 512;
    q00 = *(const half8*)(b + grow0 * 64 + lk);
    q01 = *(const half8*)(b + grow0 * 64 + 32 + lk);
    q10 = *(const half8*)(b + grow1 * 64 + lk);
    q11 = *(const half8*)(b + grow1 * 64 + 32 + lk);
  }

  // --- kn window ---
  for (int idx = tid; idx < 528; idx += 256) {
    int j = idx >> 3, c0 = (idx & 7) * 8;
    int dy = j / 22, hx = j % 22;
    int t = t0 - 1 + dy, h = h0 - 3 + hx;
    half8 v = {0, 0, 0, 0, 0, 0, 0, 0};
    if ((unsigned)t < 64u && (unsigned)h < 32u)
      v = *(const half8*)(kn + ((size_t)((batch * 64 + t) * 32 + h)) * 64 + c0);
    *(half8*)&win[j][c0] = v;
  }
  // --- Bt prologue: step 0 direct; prefetch step 1 into stB (distance-2 pipeline) ---
  *(half8*)&Bt[0][sd][skq] = *(const half8*)(Wt + (size_t)sd * 1408 + skq);
  half8 stA, stB;
  stB = *(const half8*)(Wt + (size_t)sd * 1408 + 32 + skq);
  __syncthreads();

  // --- K-loop: 22 iterations x 2 steps; prefetch distance 2 (stA/stB static names) ---
  f32x4 acc[2][4];
#pragma unroll
  for (int rt = 0; rt < 2; ++rt)
#pragma unroll
    for (int nj = 0; nj < 4; ++nj) acc[rt][nj] = (f32x4){0.f, 0.f, 0.f, 0.f};

  for (int ss = 0; ss < 22; ++ss) {
    const int sA = ss * 2, sB = sA + 1;
    const int dy = ss / 7, dxx = ss % 7;     // valid for ss<21; unused at ss=21

    // ---- step A: read Bt[0] (step sA); write Bt[1]=stB (data step sA+1); load stA=step sA+2 ----
    {
      if (sA + 2 < 44)
        stA = *(const half8*)(Wt + (size_t)sd * 1408 + (sA + 2) * 32 + skq);
      half8 bfr[4];
#pragma unroll
      for (int nj = 0; nj < 4; ++nj)
        bfr[nj] = *(const half8*)&Bt[0][nj * 16 + l15][lk];
      half8 a0, a1;
      if (ss < 21) {
        a0 = q00 * *(const half8*)&win[dy * 22 + pix0 + dxx][lk];
        a1 = q10 * *(const half8*)&win[dy * 22 + pix1 + dxx][lk];
      } else {
        a0 = q00; a1 = q10;
      }
#pragma unroll
      for (int nj = 0; nj < 4; ++nj) {
        acc[0][nj] = __builtin_amdgcn_mfma_f32_16x16x32_f16(a0, bfr[nj], acc[0][nj], 0, 0, 0);
        acc[1][nj] = __builtin_amdgcn_mfma_f32_16x16x32_f16(a1, bfr[nj], acc[1][nj], 0, 0, 0);
      }
      *(half8*)&Bt[1][sd][skq] = stB;
      __syncthreads();
    }
    // ---- step B: read Bt[1] (step sB); write Bt[0]=stA (data step sB+1); load stB=step sB+2 ----
    {
      if (sB + 2 < 44)
        stB = *(const half8*)(Wt + (size_t)sd * 1408 + (sB + 2) * 32 + skq);
      half8 bfr[4];
#pragma unroll
      for (int nj = 0; nj < 4; ++nj)
        bfr[nj] = *(const half8*)&Bt[1][nj * 16 + l15][lk];
      half8 a0, a1;
      if (ss < 21) {
        a0 = q01 * *(const half8*)&win[dy * 22 + pix0 + dxx][32 + lk];
        a1 = q11 * *(const half8*)&win[dy * 22 + pix1 + dxx][32 + lk];
      } else {
        a0 = q01; a1 = q11;
      }
#pragma unroll
      for (int nj = 0; nj < 4; ++nj) {
        acc[0][nj] = __builtin_amdgcn_mfma_f32_16x16x32_f16(a0, bfr[nj], acc[0][nj], 0, 0, 0);
        acc[1][nj] = __builtin_amdgcn_mfma_f32_16x16x32_f16(a1, bfr[nj], acc[1][nj], 0, 0, 0);
      }
      if (sB + 1 < 44) *(half8*)&Bt[0][sd][skq] = stA;
      __syncthreads();
    }
  }

  // --- kern -> LDS (own rows), Z = kern @ H2^T via MFMA (own rows) ---
  _Float16* kld = &qn_s[0][0];
  const int r0 = (lane >> 4) * 4;
#pragma unroll
  for (int rt = 0; rt < 2; ++rt) {
    int growb = (rt0 + rt) * 16;
#pragma unroll
    for (int nj = 0; nj < 4; ++nj)
#pragma unroll
      for (int r = 0; r < 4; ++r)
        kld[(growb + r0 + r) * 72 + nj * 16 + l15] = (_Float16)acc[rt][nj][r];
  }

  f32x4 accZ[2][2];
#pragma unroll
  for (int rt = 0; rt < 2; ++rt)
#pragma unroll
    for (int ct = 0; ct < 2; ++ct) accZ[rt][ct] = (f32x4){0.f, 0.f, 0.f, 0.f};
#pragma unroll
  for (int k2 = 0; k2 < 2; ++k2) {
    half8 bz[2];
#pragma unroll
    for (int ct = 0; ct < 2; ++ct)
      bz[ct] = *(const half8*)(H2h + (ct * 16 + l15) * 64 + k2 * 32 + lk);
#pragma unroll
    for (int rt = 0; rt < 2; ++rt) {
      half8 az = *(const half8*)&kld[((rt0 + rt) * 16 + l15) * 72 + k2 * 32 + lk];
#pragma unroll
      for (int ct = 0; ct < 2; ++ct)
        accZ[rt][ct] = __builtin_amdgcn_mfma_f32_16x16x32_f16(az, bz[ct], accZ[rt][ct], 0, 0, 0);
    }
  }
  __syncthreads();   // B1: phase-A LDS reads done -> overlay safe

  // --- phase B staging: Zs (from accZ), vn window, GwS ---
#pragma unroll
  for (int rt = 0; rt < 2; ++rt)
#pragma unroll
    for (int ct = 0; ct < 2; ++ct) {
      int t = ct * 16 + l15;
      if (t < 21) {
#pragma unroll
        for (int r = 0; r < 4; ++r) {
          int grow = (rt0 + rt) * 16 + r0 + r;
          Zs[((grow >> 3) * 21 + t) * 8 + (grow & 7)] = accZ[rt][ct][r];
        }
      }
    }
  for (int idx = tid; idx < 528; idx += 256) {
    int j = idx >> 3, c0 = (idx & 7) * 8;
    int dy = j / 22, hx = j % 22;
    int t = t0 - 1 + dy, h = h0 - 3 + hx;
    half8 v = {0, 0, 0, 0, 0, 0, 0, 0};
    if ((unsigned)t < 64u && (unsigned)h < 32u)
      v = *(const half8*)(vn + ((size_t)((batch * 64 + t) * 32 + h)) * 64 + c0);
    *(half8*)&win[j][c0] = v;
  }
  for (int idx = tid; idx < 168; idx += 256) {
    int t = idx >> 3, c0 = (idx & 7) * 8;
    const float* g = Gw + t * 64 + c0;
    half8 o;
#pragma unroll
    for (int j = 0; j < 8; ++j) o[j] = (_Float16)g[j];
    *(half8*)&GwS[t * 64 + c0] = o;
  }
  __syncthreads();   // B2

  // --- Gt table via MFMA Gram: 15 upper-tri 16x16 tiles over 66 win rows ---
  {
    const half8 hz = {0, 0, 0, 0, 0, 0, 0, 0};
    int c = 0;
#pragma unroll
    for (int ti = 0; ti < 5; ++ti)
#pragma unroll
      for (int tj = ti; tj < 5; ++tj, ++c) {
        if ((c & 3) == wid) {     // wave-uniform branch
          f32x4 g = {0.f, 0.f, 0.f, 0.f};
          const int ra = ti * 16 + l15, rb = tj * 16 + l15;
#pragma unroll
          for (int k2 = 0; k2 < 2; ++k2) {
            half8 av = (ra < 66) ? *(const half8*)&win[ra][k2 * 32 + lk] : hz;
            half8 bv = (rb < 66) ? *(const half8*)&win[rb][k2 * 32 + lk] : hz;
            g = __builtin_amdgcn_mfma_f32_16x16x32_f16(av, bv, g, 0, 0, 0);
          }
#pragma unroll
          for (int r = 0; r < 4; ++r) {
            int j1 = ti * 16 + r0 + r, j2 = tj * 16 + l15;
            if (j1 < 66 && j2 < 66) {
              int dy1 = j1 / 22, x1 = j1 % 22;
              int dy2 = j2 / 22, x2 = j2 % 22;
              int d = x2 - x1 + 6;
              _Float16 val = (_Float16)g[r];
              if ((unsigned)d < 13u)
                Gt[(dy1 * 3 + dy2) * 286 + x1 * 13 + d] = val;
              if (ti != tj) {          // compile-time; mirror ordered pair (j2,j1)
                int d2 = 12 - d;
                if ((unsigned)d2 < 13u)
                  Gt[(dy2 * 3 + dy1) * 286 + x2 * 13 + d2] = val;
              }
            }
          }
        }
      }
  }
  __syncthreads();   // B3

  // --- ZM[pix][t1][n] = sum_t2 Mm * Z  (round-14 version) ---
  for (int task = tid; task < 336; task += 256) {
    int pix = task / 21, t1 = task % 21;
    int dy1 = t1 / 7, dx1i = t1 % 7;
    int x1 = pix + dx1i;
    f32x4 s0 = {0.f, 0.f, 0.f, 0.f}, s1 = {0.f, 0.f, 0.f, 0.f};
#pragma unroll
    for (int t2 = 0; t2 < 21; ++t2) {
      float m = (float)Gt[(dy1 * 3 + t2 / 7) * 286 + x1 * 13 + (t2 % 7) - dx1i + 6];
      s0 += m * *(const f32x4*)&Zs[(pix * 21 + t2) * 8];
      s1 += m * *(const f32x4*)&Zs[(pix * 21 + t2) * 8 + 4];
    }
    half4 lo = {(_Float16)s0[0], (_Float16)s0[1], (_Float16)s0[2], (_Float16)s0[3]};
    half4 hi = {(_Float16)s1[0], (_Float16)s1[1], (_Float16)s1[2], (_Float16)s1[3]};
    *(half4*)&ZMs[(pix * 21 + t1) * 8]     = lo;
    *(half4*)&ZMs[(pix * 21 + t1) * 8 + 4] = hi;
  }
  __syncthreads();   // B4

  // --- out: 512 tasks of (pix, v-pair) -> 2 iterations/thread (round-14 version) ---
  for (int task = tid; task < 512; task += 256) {
    int pix = task >> 5, v0 = (task & 31) * 2;
    f32x4 a0[2] = {{0.f,0.f,0.f,0.f},{0.f,0.f,0.f,0.f}};
    f32x4 a1[2] = {{0.f,0.f,0.f,0.f},{0.f,0.f,0.f,0.f}};
#pragma unroll
    for (int t = 0; t < 21; ++t) {
      half2v sv = *(const half2v*)&win[(t / 7) * 22 + pix + (t % 7)][v0];
      half2v gw = *(const half2v*)&GwS[t * 64 + v0];
      f32x4 z0 = *(const f32x4*)&Zs[(pix * 21 + t) * 8];
      f32x4 z1 = *(const f32x4*)&Zs[(pix * 21 + t) * 8 + 4];
      half8 zm = *(const half8*)&ZMs[(pix * 21 + t) * 8];
      f32x4 m0 = {(float)zm[0], (float)zm[1], (float)zm[2], (float)zm[3]};
      f32x4 m1 = {(float)zm[4], (float)zm[5], (float)zm[6], (float)zm[7]};
#pragma unroll
      for (int j = 0; j < 2; ++j) {
        float svf = (float)sv[j], gwf = (float)gw[j];
        a0[j] += svf * z0 + gwf * m0;
        a1[j] += svf * z1 + gwf * m1;
      }
    }
#pragma unroll
    for (int j = 0; j < 2; ++j) {
      float* dst = out + (size_t)(pb + pix) * 512 + (v0 + j) * 8;
      *(f32x4*)dst = a0[j];
      *(f32x4*)(dst + 4) = a1[j];
    }
  }
}

extern "C" void kernel_launch(void* const* d_in, const int* in_sizes, int n_in,
                              void* d_out, int out_size, void* d_ws, size_t ws_size,
                              hipStream_t stream) {
  const float* x   = (const float*)d_in[0];
  const float* W1  = (const float*)d_in[1];
  const float* W2  = (const float*)d_in[2];
  const float* P1  = (const float*)d_in[3];
  const float* H1w = (const float*)d_in[4];
  const float* H2w = (const float*)d_in[5];
  const float* Gw  = (const float*)d_in[6];
  // d_in[7] = I — identity, folded algebraically.
  float* out = (float*)d_out;

  char* ws = (char*)d_ws;
  __hip_bfloat16* h_bf = (__hip_bfloat16*)(ws);             // 20,971,520
  _Float16* qn         = (_Float16*)(ws + 20971520);        // 16,777,216 (end 37,748,736)
  _Float16* kn         = (_Float16*)(ws + 37748736);        //  2,097,152
  _Float16* vn         = (_Float16*)(ws + 39845888);        //  2,097,152 (end 41,943,040)
  __hip_bfloat16* W1_bf= (__hip_bfloat16*)(ws + 41943040);  //    327,680
  __hip_bfloat16* W2_bf= (__hip_bfloat16*)(ws + 42270720);  //    819,200
  _Float16* Wt         = (_Float16*)(ws + 43089920);        //    180,224
  _Float16* H2h        = (_Float16*)(ws + 43270144);        //      4,096 (end 43,274,240)

  prep_all<<<dim3(2600), dim3(256), 0, stream>>>(W1, W2, H1w, P1, H2w,
                                                 W1_bf, W2_bf, Wt, H2h);

  gemm_st<256><<<dim3(5, 128), dim3(256), 0, stream>>>(x, (const short*)W1_bf, h_bf);
  gemm_qkv<<<dim3(5, 128), dim3(256), 0, stream>>>(
      (const short*)h_bf, (const short*)W2_bf, qn, kn, vn);

  fused_kp<<<dim3(NPIX / 16), dim3(256), 0, stream>>>(qn, kn, vn, Wt, H2h, Gw, out);
}